// Round 8
// baseline (109.566 us; speedup 1.0000x reference)
//
#include <hip/hip_runtime.h>
#include <math.h>

#define H   128
#define NS  1024
#define NE  512
#define M   1024
#define K2  2.8853900817779268f   // 2*log2(e): tanh(x) = 1 - 2/(1+exp2(K2*x))

__device__ __forceinline__ float exp2_fast(float x) {
#if __has_builtin(__builtin_amdgcn_exp2f)
    return __builtin_amdgcn_exp2f(x);
#else
    return __expf(x * 0.6931471805599453f);
#endif
}

__device__ __forceinline__ float fast_tanh(float x) {   // for k_final only
    float e = __expf(2.0f * x);
    float r = __builtin_amdgcn_rcpf(1.0f + e);
    return 1.0f - 2.0f * r;
}

// ---- transpose (+K2 scale) the weight matrices ---------------------------
__global__ __launch_bounds__(256) void k_tr(const float* __restrict__ Wc_s,
                                            const float* __restrict__ Wc_e,
                                            const float* __restrict__ W_lin,
                                            float* __restrict__ WT_s1, float* __restrict__ WT_s2,
                                            float* __restrict__ WT_e1, float* __restrict__ WT_e2,
                                            float* __restrict__ WT_lin) {
    int idx = blockIdx.x * 256 + threadIdx.x;
    if (idx < 65536) {
        int t = idx >> 14, r = idx & 16383, k = r >> 7, hh = r & 127;
        const float* src = (t < 2) ? Wc_s : Wc_e;
        int off = (t & 1) * H;
        float v = K2 * src[hh * 256 + off + k];
        float* dst = (t == 0) ? WT_s1 : (t == 1) ? WT_s2 : (t == 2) ? WT_e1 : WT_e2;
        dst[r] = v;
    } else {
        int j2 = idx - 65536;             // [0, 49152)
        int k = j2 >> 7, a = j2 & 127;
        WT_lin[j2] = W_lin[a * 384 + k];
    }
}

// ---- projections -> exp2 domain: E = exp2(K2*(XW^T + b)) -----------------
__global__ __launch_bounds__(256) void k_proj(const float* __restrict__ stmts,
                                              const float* __restrict__ eres,
                                              const float* __restrict__ attender,
                                              const float* __restrict__ WT_s1,
                                              const float* __restrict__ WT_s2,
                                              const float* __restrict__ WT_e1,
                                              const float* __restrict__ WT_e2,
                                              const float* __restrict__ bc_s,
                                              const float* __restrict__ bc_e,
                                              float* __restrict__ EA_s, float* __restrict__ EB_s,
                                              float* __restrict__ EA_e, float* __restrict__ EB_e) {
    int b = blockIdx.x;
    const float *X, *WT, *bias; float* O; int r0;
    if (b < 256)      { X = stmts;    WT = WT_s1; bias = bc_s;    O = EA_s; r0 = b * 4; }
    else if (b < 512) { X = attender; WT = WT_s2; bias = nullptr; O = EB_s; r0 = (b - 256) * 4; }
    else if (b < 640) { X = eres;     WT = WT_e1; bias = bc_e;    O = EA_e; r0 = (b - 512) * 4; }
    else              { X = attender; WT = WT_e2; bias = nullptr; O = EB_e; r0 = (b - 640) * 4; }
    __shared__ float xr[4][H];
    __shared__ float red[4][H];
    int tid  = threadIdx.x;
    int t    = tid & 127;
    int half = tid >> 7;
    float* xf = &xr[0][0];
    xf[tid]       = X[r0 * H + tid];
    xf[tid + 256] = X[r0 * H + 256 + tid];
    __syncthreads();
    float b0 = (bias && half == 0) ? K2 * bias[t] : 0.0f;   // K2-scaled bias
    float acc[4] = {b0, b0, b0, b0};
    int k0 = half * 64;
    #pragma unroll 8
    for (int k = k0; k < k0 + 64; ++k) {
        float wv = WT[k * H + t];
        #pragma unroll
        for (int r = 0; r < 4; ++r) acc[r] += xr[r][k] * wv;
    }
    if (half) {
        #pragma unroll
        for (int r = 0; r < 4; ++r) red[r][t] = acc[r];
    }
    __syncthreads();
    if (!half) {
        #pragma unroll
        for (int r = 0; r < 4; ++r) O[(r0 + r) * H + t] = exp2_fast(acc[r] + red[r][t]);
    }
}

// ---- scores via exp-product factorization, GEMM-style tiling -------------
// tanh(a+b) = 1 - 2/(1 + Ea*Eb).  St[m][n] = -2 * sum_h ws[h]/(1+Ea*Eb)
// Block tile: 32n x 32m, thread tile 2n x 2m (stride-16 interleave).
// Epilogue stages the tile in LDS and writes float4-coalesced full lines
// (avoids the RFO/partial-line write amplification seen in R7).
#define PAIR(eax, eay, ebx, eby, wx, wy, accv)                 \
    { float q0 = fmaf(eax, ebx, 1.0f);                         \
      float q1 = fmaf(eay, eby, 1.0f);                         \
      float nn = wx * q1; nn = fmaf(wy, q0, nn);               \
      float rr = __builtin_amdgcn_rcpf(q0 * q1);               \
      accv = fmaf(nn, rr, accv); }

__global__ __launch_bounds__(256, 6) void k_score(const float* __restrict__ EA_s,
                                                  const float* __restrict__ EB_s,
                                                  const float* __restrict__ ws_s,
                                                  const float* __restrict__ EA_e,
                                                  const float* __restrict__ EB_e,
                                                  const float* __restrict__ ws_e,
                                                  float* __restrict__ St_s,
                                                  float* __restrict__ St_e) {
    __shared__ float Al[32][36];   // +4 pad: b128 reads conflict-free
    __shared__ float Bl[32][36];
    int by = blockIdx.y;
    const float *EA, *EB, *wsv; float* St; int N, n0;
    if (by < 32) { EA = EA_s; EB = EB_s; wsv = ws_s; St = St_s; N = NS; n0 = by * 32; }
    else         { EA = EA_e; EB = EB_e; wsv = ws_e; St = St_e; N = NE; n0 = (by - 32) * 32; }
    int m0  = blockIdx.x * 32;
    int tid = threadIdx.x;
    int tx  = tid & 15;       // m-group
    int ty  = tid >> 4;       // n-group (0..15)
    int ar  = tid >> 3;       // staging row 0..31
    int ac  = (tid & 7) * 4;  // staging col (floats)

    float acc[2][2] = {{0.f, 0.f}, {0.f, 0.f}};

    for (int ch = 0; ch < 4; ++ch) {
        int hc = ch * 32;
        // issue stage loads early (latency overlaps the barrier)
        float4 av = *(const float4*)(EA + (size_t)(n0 + ar) * H + hc + ac);
        float4 bv = *(const float4*)(EB + (size_t)(m0 + ar) * H + hc + ac);
        __syncthreads();   // previous chunk's reads complete
        *(float4*)&Al[ar][ac] = av;
        *(float4*)&Bl[ar][ac] = bv;
        __syncthreads();

        #pragma unroll
        for (int oct = 0; oct < 4; ++oct) {
            int h0 = oct * 8;
            float4 wv0 = *(const float4*)(wsv + hc + h0);
            float4 wv1 = *(const float4*)(wsv + hc + h0 + 4);
            float w[8] = {wv0.x, wv0.y, wv0.z, wv0.w, wv1.x, wv1.y, wv1.z, wv1.w};
            float a[2][8], b[2][8];
            #pragma unroll
            for (int i = 0; i < 2; ++i) {
                float4 p = *(const float4*)&Al[ty + 16 * i][h0];
                float4 q = *(const float4*)&Al[ty + 16 * i][h0 + 4];
                a[i][0]=p.x; a[i][1]=p.y; a[i][2]=p.z; a[i][3]=p.w;
                a[i][4]=q.x; a[i][5]=q.y; a[i][6]=q.z; a[i][7]=q.w;
            }
            #pragma unroll
            for (int j = 0; j < 2; ++j) {
                float4 p = *(const float4*)&Bl[tx + 16 * j][h0];
                float4 q = *(const float4*)&Bl[tx + 16 * j][h0 + 4];
                b[j][0]=p.x; b[j][1]=p.y; b[j][2]=p.z; b[j][3]=p.w;
                b[j][4]=q.x; b[j][5]=q.y; b[j][6]=q.z; b[j][7]=q.w;
            }
            #pragma unroll
            for (int j = 0; j < 2; ++j)
                #pragma unroll
                for (int i = 0; i < 2; ++i) {
                    PAIR(a[i][0], a[i][1], b[j][0], b[j][1], w[0], w[1], acc[i][j]);
                    PAIR(a[i][2], a[i][3], b[j][2], b[j][3], w[2], w[3], acc[i][j]);
                    PAIR(a[i][4], a[i][5], b[j][4], b[j][5], w[4], w[5], acc[i][j]);
                    PAIR(a[i][6], a[i][7], b[j][6], b[j][7], w[6], w[7], acc[i][j]);
                }
        }
    }

    // ---- epilogue: stage tile in LDS (reuse Al), write coalesced lines ----
    __syncthreads();
    #pragma unroll
    for (int j = 0; j < 2; ++j)
        #pragma unroll
        for (int i = 0; i < 2; ++i)
            Al[tx + 16 * j][ty + 16 * i] = -2.0f * acc[i][j];   // [m_local][n_local]
    __syncthreads();
    {
        int r = tid >> 3;            // m_local 0..31
        int c = (tid & 7) * 4;       // n_local
        float4 o = *(const float4*)&Al[r][c];
        *(float4*)(St + (size_t)(m0 + r) * N + n0 + c) = o;
    }
}

// ---- fused softmax-stats + context + final MLP ---------------------------
#define TMD 4
__device__ __forceinline__ void reduce4(float v[TMD], bool domax, float (*scr)[TMD]) {
    #pragma unroll
    for (int off = 32; off > 0; off >>= 1) {
        #pragma unroll
        for (int j = 0; j < TMD; ++j) {
            float o = __shfl_xor(v[j], off, 64);
            v[j] = domax ? fmaxf(v[j], o) : (v[j] + o);
        }
    }
    int wv = threadIdx.x >> 6;     // 0..15
    if ((threadIdx.x & 63) == 0) {
        #pragma unroll
        for (int j = 0; j < TMD; ++j) scr[wv][j] = v[j];
    }
    __syncthreads();
    #pragma unroll
    for (int j = 0; j < TMD; ++j) {
        float r = scr[0][j];
        #pragma unroll
        for (int i = 1; i < 16; ++i) r = domax ? fmaxf(r, scr[i][j]) : (r + scr[i][j]);
        v[j] = r;
    }
    __syncthreads();
}

__global__ __launch_bounds__(1024) void k_attend(const float* __restrict__ St_s,
                                                 const float* __restrict__ St_e,
                                                 const float* __restrict__ stmts,
                                                 const float* __restrict__ eres,
                                                 const float* __restrict__ attender,
                                                 const float* __restrict__ WT_lin,
                                                 const float* __restrict__ b_lin,
                                                 const float* __restrict__ W_coh,
                                                 const float* __restrict__ b_coh,
                                                 float* __restrict__ out) {
    __shared__ float wls[1024][TMD];       // 16 KB, 16B rows: b128 in/out
    __shared__ float part[8][TMD][H];
    __shared__ float feats[TMD][3 * H];
    __shared__ float scr[16][TMD];
    __shared__ float redv[512];
    __shared__ float red8[8];
    int m0  = blockIdx.x * TMD;
    int tid = threadIdx.x;
    int h   = tid & (H - 1);
    int g   = tid >> 7;    // 0..7

    if (tid < TMD * H) feats[tid >> 7][tid & (H - 1)] = attender[(m0 + (tid >> 7)) * H + (tid & (H - 1))];

    float vs[TMD], ve[TMD];
    #pragma unroll
    for (int j = 0; j < TMD; ++j) vs[j] = St_s[(size_t)(m0 + j) * NS + tid];
    #pragma unroll
    for (int j = 0; j < TMD; ++j) ve[j] = (tid < NE) ? St_e[(size_t)(m0 + j) * NE + tid] : -1e30f;

    float mxs[TMD], sm_s[TMD], rz_s[TMD], w_s[TMD];
    #pragma unroll
    for (int j = 0; j < TMD; ++j) mxs[j] = vs[j];
    reduce4(mxs, true, scr);
    #pragma unroll
    for (int j = 0; j < TMD; ++j) { w_s[j] = __expf(vs[j] - mxs[j]); sm_s[j] = w_s[j]; }
    reduce4(sm_s, false, scr);
    #pragma unroll
    for (int j = 0; j < TMD; ++j) rz_s[j] = __builtin_amdgcn_rcpf(sm_s[j]);

    float mxe[TMD], sm_e[TMD], rz_e[TMD], w_e[TMD];
    #pragma unroll
    for (int j = 0; j < TMD; ++j) mxe[j] = ve[j];
    reduce4(mxe, true, scr);
    #pragma unroll
    for (int j = 0; j < TMD; ++j) { w_e[j] = __expf(ve[j] - mxe[j]); sm_e[j] = w_e[j]; }
    reduce4(sm_e, false, scr);
    #pragma unroll
    for (int j = 0; j < TMD; ++j) rz_e[j] = __builtin_amdgcn_rcpf(sm_e[j]);

    // ---- ctx_s ----
    *(float4*)&wls[tid][0] = make_float4(w_s[0], w_s[1], w_s[2], w_s[3]);
    __syncthreads();
    {
        float acc[TMD] = {0.f, 0.f, 0.f, 0.f};
        const float* Xb = stmts + (size_t)(g * 128) * H + h;
        #pragma unroll 8
        for (int nn = 0; nn < 128; ++nn) {
            float x = Xb[(size_t)nn * H];
            float4 w4 = *(const float4*)&wls[g * 128 + nn][0];
            acc[0] += w4.x * x; acc[1] += w4.y * x;
            acc[2] += w4.z * x; acc[3] += w4.w * x;
        }
        #pragma unroll
        for (int j = 0; j < TMD; ++j) part[g][j][h] = acc[j];
    }
    __syncthreads();
    if (tid < 512) {
        int j = tid >> 7, hh = tid & 127;
        float s = 0.f;
        #pragma unroll
        for (int gg = 0; gg < 8; ++gg) s += part[gg][j][hh];
        feats[j][H + hh] = s * rz_s[j];
    }
    __syncthreads();

    // ---- ctx_e ----
    *(float4*)&wls[tid][0] = make_float4(w_e[0], w_e[1], w_e[2], w_e[3]);
    __syncthreads();
    {
        float acc[TMD] = {0.f, 0.f, 0.f, 0.f};
        const float* Xb = eres + (size_t)(g * 64) * H + h;
        #pragma unroll 8
        for (int nn = 0; nn < 64; ++nn) {
            float x = Xb[(size_t)nn * H];
            float4 w4 = *(const float4*)&wls[g * 64 + nn][0];
            acc[0] += w4.x * x; acc[1] += w4.y * x;
            acc[2] += w4.z * x; acc[3] += w4.w * x;
        }
        #pragma unroll
        for (int j = 0; j < TMD; ++j) part[g][j][h] = acc[j];
    }
    __syncthreads();
    if (tid < 512) {
        int j = tid >> 7, hh = tid & 127;
        float s = 0.f;
        #pragma unroll
        for (int gg = 0; gg < 8; ++gg) s += part[gg][j][hh];
        feats[j][2 * H + hh] = s * rz_e[j];
    }
    __syncthreads();

    // ---- final MLP + coherence ----
    {
        int a    = tid & 127;
        int jm   = (tid >> 7) & 3;
        int half = tid >> 9;
        float acc = half ? 0.f : b_lin[a];
        int k0 = half * 192;
        #pragma unroll 8
        for (int k = k0; k < k0 + 192; ++k)
            acc += feats[jm][k] * WT_lin[k * H + a];
        if (half) redv[tid & 511] = acc;
        __syncthreads();
        if (!half) {
            acc += redv[tid];
            float v = fast_tanh(acc) * W_coh[a];
            #pragma unroll
            for (int off = 32; off > 0; off >>= 1) v += __shfl_down(v, off, 64);
            if ((tid & 63) == 0) red8[tid >> 6] = v;
        }
        __syncthreads();
        if (tid < TMD) out[m0 + tid] = red8[2 * tid] + red8[2 * tid + 1] + b_coh[0];
    }
}

extern "C" void kernel_launch(void* const* d_in, const int* in_sizes, int n_in,
                              void* d_out, int out_size, void* d_ws, size_t ws_size,
                              hipStream_t stream) {
    const float* stmts    = (const float*)d_in[0];
    const float* eres     = (const float*)d_in[1];
    const float* attender = (const float*)d_in[2];
    const float* Wc_s     = (const float*)d_in[3];
    const float* bc_s     = (const float*)d_in[4];
    const float* ws_s     = (const float*)d_in[5];
    const float* Wc_e     = (const float*)d_in[7];
    const float* bc_e     = (const float*)d_in[8];
    const float* ws_e     = (const float*)d_in[9];
    const float* W_lin    = (const float*)d_in[11];
    const float* b_lin    = (const float*)d_in[12];
    const float* W_coh    = (const float*)d_in[13];
    const float* b_coh    = (const float*)d_in[14];
    float* out = (float*)d_out;

    float* ws    = (float*)d_ws;
    float* WT_s1 = ws;
    float* WT_s2 = WT_s1 + H * H;
    float* WT_e1 = WT_s2 + H * H;
    float* WT_e2 = WT_e1 + H * H;
    float* WT_li = WT_e2 + H * H;             // 384*128
    float* EA_s  = WT_li + 3 * H * H;
    float* EB_s  = EA_s + NS * H;
    float* EA_e  = EB_s + M * H;
    float* EB_e  = EA_e + NE * H;
    float* St_s  = EB_e + M * H;
    float* St_e  = St_s + (size_t)M * NS;

    k_tr<<<448, 256, 0, stream>>>(Wc_s, Wc_e, W_lin, WT_s1, WT_s2, WT_e1, WT_e2, WT_li);
    k_proj<<<896, 256, 0, stream>>>(stmts, eres, attender, WT_s1, WT_s2, WT_e1, WT_e2,
                                    bc_s, bc_e, EA_s, EB_s, EA_e, EB_e);
    k_score<<<dim3(32, 48), 256, 0, stream>>>(EA_s, EB_s, ws_s, EA_e, EB_e, ws_e, St_s, St_e);
    k_attend<<<M / TMD, 1024, 0, stream>>>(St_s, St_e, stmts, eres, attender, WT_li,
                                           b_lin, W_coh, b_coh, out);
}

// Round 9
// 87.086 us; speedup vs baseline: 1.2581x; 1.2581x over previous
//
#include <hip/hip_runtime.h>
#include <math.h>

#define H   128
#define NS  1024
#define NE  512
#define M   1024
#define K2  2.8853900817779268f   // 2*log2(e): tanh(x) = 1 - 2/(1+exp2(K2*x))

__device__ __forceinline__ float exp2_fast(float x) {
#if __has_builtin(__builtin_amdgcn_exp2f)
    return __builtin_amdgcn_exp2f(x);
#else
    return __expf(x * 0.6931471805599453f);
#endif
}

__device__ __forceinline__ float fast_tanh(float x) {   // for k_final only
    float e = __expf(2.0f * x);
    float r = __builtin_amdgcn_rcpf(1.0f + e);
    return 1.0f - 2.0f * r;
}

// ---- transpose (+K2 scale) the weight matrices ---------------------------
__global__ __launch_bounds__(256) void k_tr(const float* __restrict__ Wc_s,
                                            const float* __restrict__ Wc_e,
                                            const float* __restrict__ W_lin,
                                            float* __restrict__ WT_s1, float* __restrict__ WT_s2,
                                            float* __restrict__ WT_e1, float* __restrict__ WT_e2,
                                            float* __restrict__ WT_lin) {
    int idx = blockIdx.x * 256 + threadIdx.x;
    if (idx < 65536) {
        int t = idx >> 14, r = idx & 16383, k = r >> 7, hh = r & 127;
        const float* src = (t < 2) ? Wc_s : Wc_e;
        int off = (t & 1) * H;
        float v = K2 * src[hh * 256 + off + k];
        float* dst = (t == 0) ? WT_s1 : (t == 1) ? WT_s2 : (t == 2) ? WT_e1 : WT_e2;
        dst[r] = v;
    } else {
        int j2 = idx - 65536;             // [0, 49152)
        int k = j2 >> 7, a = j2 & 127;
        WT_lin[j2] = W_lin[a * 384 + k];
    }
}

// ---- projections -> exp2 domain: E = exp2(K2*(XW^T + b)) -----------------
__global__ __launch_bounds__(256) void k_proj(const float* __restrict__ stmts,
                                              const float* __restrict__ eres,
                                              const float* __restrict__ attender,
                                              const float* __restrict__ WT_s1,
                                              const float* __restrict__ WT_s2,
                                              const float* __restrict__ WT_e1,
                                              const float* __restrict__ WT_e2,
                                              const float* __restrict__ bc_s,
                                              const float* __restrict__ bc_e,
                                              float* __restrict__ EA_s, float* __restrict__ EB_s,
                                              float* __restrict__ EA_e, float* __restrict__ EB_e) {
    int b = blockIdx.x;
    const float *X, *WT, *bias; float* O; int r0;
    if (b < 256)      { X = stmts;    WT = WT_s1; bias = bc_s;    O = EA_s; r0 = b * 4; }
    else if (b < 512) { X = attender; WT = WT_s2; bias = nullptr; O = EB_s; r0 = (b - 256) * 4; }
    else if (b < 640) { X = eres;     WT = WT_e1; bias = bc_e;    O = EA_e; r0 = (b - 512) * 4; }
    else              { X = attender; WT = WT_e2; bias = nullptr; O = EB_e; r0 = (b - 640) * 4; }
    __shared__ float xr[4][H];
    __shared__ float red[4][H];
    int tid  = threadIdx.x;
    int t    = tid & 127;
    int half = tid >> 7;
    float* xf = &xr[0][0];
    xf[tid]       = X[r0 * H + tid];
    xf[tid + 256] = X[r0 * H + 256 + tid];
    __syncthreads();
    float b0 = (bias && half == 0) ? K2 * bias[t] : 0.0f;   // K2-scaled bias
    float acc[4] = {b0, b0, b0, b0};
    int k0 = half * 64;
    #pragma unroll 8
    for (int k = k0; k < k0 + 64; ++k) {
        float wv = WT[k * H + t];
        #pragma unroll
        for (int r = 0; r < 4; ++r) acc[r] += xr[r][k] * wv;
    }
    if (half) {
        #pragma unroll
        for (int r = 0; r < 4; ++r) red[r][t] = acc[r];
    }
    __syncthreads();
    if (!half) {
        #pragma unroll
        for (int r = 0; r < 4; ++r) O[(r0 + r) * H + t] = exp2_fast(acc[r] + red[r][t]);
    }
}

// ---- scores via exp-product factorization, GEMM-style tiling -------------
// tanh(a+b) = 1 - 2/(1 + Ea*Eb).  St[m][n] = -2 * sum_h ws[h]/(1+Ea*Eb)
// Block tile: 32n x 64m (R7-proven body, 64 VGPR). Thread tile: 2n x 4m.
// Epilogue (only change vs R7): stage tile in Bl, write full 128B segments.
#define PAIR(eax, eay, ebx, eby, wx, wy, accv)                 \
    { float q0 = fmaf(eax, ebx, 1.0f);                         \
      float q1 = fmaf(eay, eby, 1.0f);                         \
      float nn = wx * q1; nn = fmaf(wy, q0, nn);               \
      float rr = __builtin_amdgcn_rcpf(q0 * q1);               \
      accv = fmaf(nn, rr, accv); }

__global__ __launch_bounds__(256, 4) void k_score(const float* __restrict__ EA_s,
                                                  const float* __restrict__ EB_s,
                                                  const float* __restrict__ ws_s,
                                                  const float* __restrict__ EA_e,
                                                  const float* __restrict__ EB_e,
                                                  const float* __restrict__ ws_e,
                                                  float* __restrict__ St_s,
                                                  float* __restrict__ St_e) {
    __shared__ float Al[32][36];   // [row][36]: +4 pad keeps b128 16B-aligned
    __shared__ float Bl[64][36];
    int by = blockIdx.y;
    const float *EA, *EB, *wsv; float* St; int N, n0;
    if (by < 32) { EA = EA_s; EB = EB_s; wsv = ws_s; St = St_s; N = NS; n0 = by * 32; }
    else         { EA = EA_e; EB = EB_e; wsv = ws_e; St = St_e; N = NE; n0 = (by - 32) * 32; }
    int m0  = blockIdx.x * 64;
    int tid = threadIdx.x;
    int tx  = tid & 15;    // m-group
    int ty  = tid >> 4;    // n-group
    int ar  = tid >> 3;    // staging row 0..31
    int ac  = (tid & 7) * 4;  // staging col (floats)

    float acc[2][4] = {{0.f,0.f,0.f,0.f},{0.f,0.f,0.f,0.f}};

    for (int ch = 0; ch < 4; ++ch) {
        int hc = ch * 32;
        // issue stage loads early (L2 latency overlaps the barrier)
        float4 av  = *(const float4*)(EA + (size_t)(n0 + ar) * H + hc + ac);
        float4 bv0 = *(const float4*)(EB + (size_t)(m0 + ar) * H + hc + ac);
        float4 bv1 = *(const float4*)(EB + (size_t)(m0 + 32 + ar) * H + hc + ac);
        __syncthreads();   // previous chunk's reads complete
        *(float4*)&Al[ar][ac]      = av;
        *(float4*)&Bl[ar][ac]      = bv0;
        *(float4*)&Bl[32 + ar][ac] = bv1;
        __syncthreads();

        #pragma unroll
        for (int oct = 0; oct < 4; ++oct) {
            int h0 = oct * 8;
            float4 wv0 = *(const float4*)(wsv + hc + h0);
            float4 wv1 = *(const float4*)(wsv + hc + h0 + 4);
            float w[8] = {wv0.x, wv0.y, wv0.z, wv0.w, wv1.x, wv1.y, wv1.z, wv1.w};
            float a[2][8];
            #pragma unroll
            for (int i = 0; i < 2; ++i) {
                float4 p = *(const float4*)&Al[ty + 16 * i][h0];
                float4 q = *(const float4*)&Al[ty + 16 * i][h0 + 4];
                a[i][0]=p.x; a[i][1]=p.y; a[i][2]=p.z; a[i][3]=p.w;
                a[i][4]=q.x; a[i][5]=q.y; a[i][6]=q.z; a[i][7]=q.w;
            }
            float bfr[4][8];
            #pragma unroll
            for (int j = 0; j < 4; ++j) {
                float4 p = *(const float4*)&Bl[tx + 16 * j][h0];
                float4 q = *(const float4*)&Bl[tx + 16 * j][h0 + 4];
                bfr[j][0]=p.x; bfr[j][1]=p.y; bfr[j][2]=p.z; bfr[j][3]=p.w;
                bfr[j][4]=q.x; bfr[j][5]=q.y; bfr[j][6]=q.z; bfr[j][7]=q.w;
            }
            #pragma unroll
            for (int j = 0; j < 4; ++j) {
                #pragma unroll
                for (int i = 0; i < 2; ++i) {
                    PAIR(a[i][0], a[i][1], bfr[j][0], bfr[j][1], w[0], w[1], acc[i][j]);
                    PAIR(a[i][2], a[i][3], bfr[j][2], bfr[j][3], w[2], w[3], acc[i][j]);
                    PAIR(a[i][4], a[i][5], bfr[j][4], bfr[j][5], w[4], w[5], acc[i][j]);
                    PAIR(a[i][6], a[i][7], bfr[j][6], bfr[j][7], w[6], w[7], acc[i][j]);
                }
            }
        }
    }

    // ---- epilogue: stage [64m][32n] tile in Bl, write full-line float4 ----
    __syncthreads();
    #pragma unroll
    for (int j = 0; j < 4; ++j)
        #pragma unroll
        for (int i = 0; i < 2; ++i)
            Bl[tx + 16 * j][ty + 16 * i] = -2.0f * acc[i][j];
    __syncthreads();
    {
        int r = tid >> 3;            // 0..31
        int c = (tid & 7) * 4;       // 0..28
        float4 o0 = *(const float4*)&Bl[r][c];
        *(float4*)(St + (size_t)(m0 + r) * N + n0 + c) = o0;
        float4 o1 = *(const float4*)&Bl[r + 32][c];
        *(float4*)(St + (size_t)(m0 + r + 32) * N + n0 + c) = o1;
    }
}

// ---- fused softmax-stats + context + final MLP ---------------------------
#define TMD 4
__device__ __forceinline__ void reduce4(float v[TMD], bool domax, float (*scr)[TMD]) {
    #pragma unroll
    for (int off = 32; off > 0; off >>= 1) {
        #pragma unroll
        for (int j = 0; j < TMD; ++j) {
            float o = __shfl_xor(v[j], off, 64);
            v[j] = domax ? fmaxf(v[j], o) : (v[j] + o);
        }
    }
    int wv = threadIdx.x >> 6;     // 0..15
    if ((threadIdx.x & 63) == 0) {
        #pragma unroll
        for (int j = 0; j < TMD; ++j) scr[wv][j] = v[j];
    }
    __syncthreads();
    #pragma unroll
    for (int j = 0; j < TMD; ++j) {
        float r = scr[0][j];
        #pragma unroll
        for (int i = 1; i < 16; ++i) r = domax ? fmaxf(r, scr[i][j]) : (r + scr[i][j]);
        v[j] = r;
    }
    __syncthreads();
}

__global__ __launch_bounds__(1024) void k_attend(const float* __restrict__ St_s,
                                                 const float* __restrict__ St_e,
                                                 const float* __restrict__ stmts,
                                                 const float* __restrict__ eres,
                                                 const float* __restrict__ attender,
                                                 const float* __restrict__ WT_lin,
                                                 const float* __restrict__ b_lin,
                                                 const float* __restrict__ W_coh,
                                                 const float* __restrict__ b_coh,
                                                 float* __restrict__ out) {
    __shared__ float wls[1024][TMD];       // 16 KB, 16B rows: b128 in/out
    __shared__ float part[8][TMD][H];
    __shared__ float feats[TMD][3 * H];
    __shared__ float scr[16][TMD];
    __shared__ float redv[512];
    __shared__ float red8[8];
    int m0  = blockIdx.x * TMD;
    int tid = threadIdx.x;
    int h   = tid & (H - 1);
    int g   = tid >> 7;    // 0..7

    if (tid < TMD * H) feats[tid >> 7][tid & (H - 1)] = attender[(m0 + (tid >> 7)) * H + (tid & (H - 1))];

    float vs[TMD], ve[TMD];
    #pragma unroll
    for (int j = 0; j < TMD; ++j) vs[j] = St_s[(size_t)(m0 + j) * NS + tid];
    #pragma unroll
    for (int j = 0; j < TMD; ++j) ve[j] = (tid < NE) ? St_e[(size_t)(m0 + j) * NE + tid] : -1e30f;

    float mxs[TMD], sm_s[TMD], rz_s[TMD], w_s[TMD];
    #pragma unroll
    for (int j = 0; j < TMD; ++j) mxs[j] = vs[j];
    reduce4(mxs, true, scr);
    #pragma unroll
    for (int j = 0; j < TMD; ++j) { w_s[j] = __expf(vs[j] - mxs[j]); sm_s[j] = w_s[j]; }
    reduce4(sm_s, false, scr);
    #pragma unroll
    for (int j = 0; j < TMD; ++j) rz_s[j] = __builtin_amdgcn_rcpf(sm_s[j]);

    float mxe[TMD], sm_e[TMD], rz_e[TMD], w_e[TMD];
    #pragma unroll
    for (int j = 0; j < TMD; ++j) mxe[j] = ve[j];
    reduce4(mxe, true, scr);
    #pragma unroll
    for (int j = 0; j < TMD; ++j) { w_e[j] = __expf(ve[j] - mxe[j]); sm_e[j] = w_e[j]; }
    reduce4(sm_e, false, scr);
    #pragma unroll
    for (int j = 0; j < TMD; ++j) rz_e[j] = __builtin_amdgcn_rcpf(sm_e[j]);

    // ---- ctx_s ----
    *(float4*)&wls[tid][0] = make_float4(w_s[0], w_s[1], w_s[2], w_s[3]);
    __syncthreads();
    {
        float acc[TMD] = {0.f, 0.f, 0.f, 0.f};
        const float* Xb = stmts + (size_t)(g * 128) * H + h;
        #pragma unroll 8
        for (int nn = 0; nn < 128; ++nn) {
            float x = Xb[(size_t)nn * H];
            float4 w4 = *(const float4*)&wls[g * 128 + nn][0];
            acc[0] += w4.x * x; acc[1] += w4.y * x;
            acc[2] += w4.z * x; acc[3] += w4.w * x;
        }
        #pragma unroll
        for (int j = 0; j < TMD; ++j) part[g][j][h] = acc[j];
    }
    __syncthreads();
    if (tid < 512) {
        int j = tid >> 7, hh = tid & 127;
        float s = 0.f;
        #pragma unroll
        for (int gg = 0; gg < 8; ++gg) s += part[gg][j][hh];
        feats[j][H + hh] = s * rz_s[j];
    }
    __syncthreads();

    // ---- ctx_e ----
    *(float4*)&wls[tid][0] = make_float4(w_e[0], w_e[1], w_e[2], w_e[3]);
    __syncthreads();
    {
        float acc[TMD] = {0.f, 0.f, 0.f, 0.f};
        const float* Xb = eres + (size_t)(g * 64) * H + h;
        #pragma unroll 8
        for (int nn = 0; nn < 64; ++nn) {
            float x = Xb[(size_t)nn * H];
            float4 w4 = *(const float4*)&wls[g * 64 + nn][0];
            acc[0] += w4.x * x; acc[1] += w4.y * x;
            acc[2] += w4.z * x; acc[3] += w4.w * x;
        }
        #pragma unroll
        for (int j = 0; j < TMD; ++j) part[g][j][h] = acc[j];
    }
    __syncthreads();
    if (tid < 512) {
        int j = tid >> 7, hh = tid & 127;
        float s = 0.f;
        #pragma unroll
        for (int gg = 0; gg < 8; ++gg) s += part[gg][j][hh];
        feats[j][2 * H + hh] = s * rz_e[j];
    }
    __syncthreads();

    // ---- final MLP + coherence ----
    {
        int a    = tid & 127;
        int jm   = (tid >> 7) & 3;
        int half = tid >> 9;
        float acc = half ? 0.f : b_lin[a];
        int k0 = half * 192;
        #pragma unroll 8
        for (int k = k0; k < k0 + 192; ++k)
            acc += feats[jm][k] * WT_lin[k * H + a];
        if (half) redv[tid & 511] = acc;
        __syncthreads();
        if (!half) {
            acc += redv[tid];
            float v = fast_tanh(acc) * W_coh[a];
            #pragma unroll
            for (int off = 32; off > 0; off >>= 1) v += __shfl_down(v, off, 64);
            if ((tid & 63) == 0) red8[tid >> 6] = v;
        }
        __syncthreads();
        if (tid < TMD) out[m0 + tid] = red8[2 * tid] + red8[2 * tid + 1] + b_coh[0];
    }
}

extern "C" void kernel_launch(void* const* d_in, const int* in_sizes, int n_in,
                              void* d_out, int out_size, void* d_ws, size_t ws_size,
                              hipStream_t stream) {
    const float* stmts    = (const float*)d_in[0];
    const float* eres     = (const float*)d_in[1];
    const float* attender = (const float*)d_in[2];
    const float* Wc_s     = (const float*)d_in[3];
    const float* bc_s     = (const float*)d_in[4];
    const float* ws_s     = (const float*)d_in[5];
    const float* Wc_e     = (const float*)d_in[7];
    const float* bc_e     = (const float*)d_in[8];
    const float* ws_e     = (const float*)d_in[9];
    const float* W_lin    = (const float*)d_in[11];
    const float* b_lin    = (const float*)d_in[12];
    const float* W_coh    = (const float*)d_in[13];
    const float* b_coh    = (const float*)d_in[14];
    float* out = (float*)d_out;

    float* ws    = (float*)d_ws;
    float* WT_s1 = ws;
    float* WT_s2 = WT_s1 + H * H;
    float* WT_e1 = WT_s2 + H * H;
    float* WT_e2 = WT_e1 + H * H;
    float* WT_li = WT_e2 + H * H;             // 384*128
    float* EA_s  = WT_li + 3 * H * H;
    float* EB_s  = EA_s + NS * H;
    float* EA_e  = EB_s + M * H;
    float* EB_e  = EA_e + NE * H;
    float* St_s  = EB_e + M * H;
    float* St_e  = St_s + (size_t)M * NS;

    k_tr<<<448, 256, 0, stream>>>(Wc_s, Wc_e, W_lin, WT_s1, WT_s2, WT_e1, WT_e2, WT_li);
    k_proj<<<896, 256, 0, stream>>>(stmts, eres, attender, WT_s1, WT_s2, WT_e1, WT_e2,
                                    bc_s, bc_e, EA_s, EB_s, EA_e, EB_e);
    k_score<<<dim3(16, 48), 256, 0, stream>>>(EA_s, EB_s, ws_s, EA_e, EB_e, ws_e, St_s, St_e);
    k_attend<<<M / TMD, 1024, 0, stream>>>(St_s, St_e, stmts, eres, attender, WT_li,
                                           b_lin, W_coh, b_coh, out);
}

// Round 11
// 68.950 us; speedup vs baseline: 1.5891x; 1.2630x over previous
//
#include <hip/hip_runtime.h>
#include <math.h>

#define H   128
#define NS  1024
#define NE  512
#define M   1024
#define K2  2.8853900817779268f   // 2*log2(e): tanh(x) = 1 - 2/(1+exp2(K2*x))

typedef float v4f __attribute__((ext_vector_type(4)));   // nt-builtin-compatible

__device__ __forceinline__ float exp2_fast(float x) {
#if __has_builtin(__builtin_amdgcn_exp2f)
    return __builtin_amdgcn_exp2f(x);
#else
    return __expf(x * 0.6931471805599453f);
#endif
}

__device__ __forceinline__ float fast_tanh(float x) {   // for k_final only
    float e = __expf(2.0f * x);
    float r = __builtin_amdgcn_rcpf(1.0f + e);
    return 1.0f - 2.0f * r;
}

// ---- transpose (+K2 scale) the weight matrices ---------------------------
__global__ __launch_bounds__(256) void k_tr(const float* __restrict__ Wc_s,
                                            const float* __restrict__ Wc_e,
                                            const float* __restrict__ W_lin,
                                            float* __restrict__ WT_s1, float* __restrict__ WT_s2,
                                            float* __restrict__ WT_e1, float* __restrict__ WT_e2,
                                            float* __restrict__ WT_lin) {
    int idx = blockIdx.x * 256 + threadIdx.x;
    if (idx < 65536) {
        int t = idx >> 14, r = idx & 16383, k = r >> 7, hh = r & 127;
        const float* src = (t < 2) ? Wc_s : Wc_e;
        int off = (t & 1) * H;
        float v = K2 * src[hh * 256 + off + k];
        float* dst = (t == 0) ? WT_s1 : (t == 1) ? WT_s2 : (t == 2) ? WT_e1 : WT_e2;
        dst[r] = v;
    } else {
        int j2 = idx - 65536;             // [0, 49152)
        int k = j2 >> 7, a = j2 & 127;
        WT_lin[j2] = W_lin[a * 384 + k];
    }
}

// ---- projections -> exp2 domain: E = exp2(K2*(XW^T + b)) -----------------
__global__ __launch_bounds__(256) void k_proj(const float* __restrict__ stmts,
                                              const float* __restrict__ eres,
                                              const float* __restrict__ attender,
                                              const float* __restrict__ WT_s1,
                                              const float* __restrict__ WT_s2,
                                              const float* __restrict__ WT_e1,
                                              const float* __restrict__ WT_e2,
                                              const float* __restrict__ bc_s,
                                              const float* __restrict__ bc_e,
                                              float* __restrict__ EA_s, float* __restrict__ EB_s,
                                              float* __restrict__ EA_e, float* __restrict__ EB_e) {
    int b = blockIdx.x;
    const float *X, *WT, *bias; float* O; int r0;
    if (b < 256)      { X = stmts;    WT = WT_s1; bias = bc_s;    O = EA_s; r0 = b * 4; }
    else if (b < 512) { X = attender; WT = WT_s2; bias = nullptr; O = EB_s; r0 = (b - 256) * 4; }
    else if (b < 640) { X = eres;     WT = WT_e1; bias = bc_e;    O = EA_e; r0 = (b - 512) * 4; }
    else              { X = attender; WT = WT_e2; bias = nullptr; O = EB_e; r0 = (b - 640) * 4; }
    __shared__ float xr[4][H];
    __shared__ float red[4][H];
    int tid  = threadIdx.x;
    int t    = tid & 127;
    int half = tid >> 7;
    float* xf = &xr[0][0];
    xf[tid]       = X[r0 * H + tid];
    xf[tid + 256] = X[r0 * H + 256 + tid];
    __syncthreads();
    float b0 = (bias && half == 0) ? K2 * bias[t] : 0.0f;   // K2-scaled bias
    float acc[4] = {b0, b0, b0, b0};
    int k0 = half * 64;
    #pragma unroll 8
    for (int k = k0; k < k0 + 64; ++k) {
        float wv = WT[k * H + t];
        #pragma unroll
        for (int r = 0; r < 4; ++r) acc[r] += xr[r][k] * wv;
    }
    if (half) {
        #pragma unroll
        for (int r = 0; r < 4; ++r) red[r][t] = acc[r];
    }
    __syncthreads();
    if (!half) {
        #pragma unroll
        for (int r = 0; r < 4; ++r) O[(r0 + r) * H + t] = exp2_fast(acc[r] + red[r][t]);
    }
}

// ---- scores via exp-product factorization, GEMM-style tiling -------------
// tanh(a+b) = 1 - 2/(1 + Ea*Eb).  St[m][n] = -2 * sum_h ws[h]/(1+Ea*Eb)
// Block tile: 32n x 64m, thread tile 2n x 4m. Register double-buffer:
// chunk ch+1's loads issue BEFORE chunk ch's compute (latency hidden).
// St written via nontemporal stores (write-once data, keep L2 for E).
#define PAIR(eax, eay, ebx, eby, wx, wy, accv)                 \
    { float q0 = fmaf(eax, ebx, 1.0f);                         \
      float q1 = fmaf(eay, eby, 1.0f);                         \
      float nn = wx * q1; nn = fmaf(wy, q0, nn);               \
      float rr = __builtin_amdgcn_rcpf(q0 * q1);               \
      accv = fmaf(nn, rr, accv); }

__global__ __launch_bounds__(256, 3) void k_score(const float* __restrict__ EA_s,
                                                  const float* __restrict__ EB_s,
                                                  const float* __restrict__ ws_s,
                                                  const float* __restrict__ EA_e,
                                                  const float* __restrict__ EB_e,
                                                  const float* __restrict__ ws_e,
                                                  float* __restrict__ St_s,
                                                  float* __restrict__ St_e) {
    __shared__ float Al[32][36];   // +4 pad: b128 reads conflict-free
    __shared__ float Bl[64][36];
    int by = blockIdx.y;
    const float *EA, *EB, *wsv; float* St; int N, n0;
    if (by < 32) { EA = EA_s; EB = EB_s; wsv = ws_s; St = St_s; N = NS; n0 = by * 32; }
    else         { EA = EA_e; EB = EB_e; wsv = ws_e; St = St_e; N = NE; n0 = (by - 32) * 32; }
    int m0  = blockIdx.x * 64;
    int tid = threadIdx.x;
    int tx  = tid & 15;       // m-group
    int ty  = tid >> 4;       // n-group
    int ar  = tid >> 3;       // staging row 0..31
    int ac  = (tid & 7) * 4;  // staging col (floats)

    const float* pa  = EA + (size_t)(n0 + ar) * H + ac;
    const float* pb0 = EB + (size_t)(m0 + ar) * H + ac;
    const float* pb1 = EB + (size_t)(m0 + 32 + ar) * H + ac;

    float4 av  = *(const float4*)(pa);
    float4 bv0 = *(const float4*)(pb0);
    float4 bv1 = *(const float4*)(pb1);

    float acc[2][4] = {{0.f,0.f,0.f,0.f},{0.f,0.f,0.f,0.f}};

    for (int ch = 0; ch < 4; ++ch) {
        if (ch) __syncthreads();        // previous chunk's readers done
        *(float4*)&Al[ar][ac]      = av;
        *(float4*)&Bl[ar][ac]      = bv0;
        *(float4*)&Bl[32 + ar][ac] = bv1;
        __syncthreads();
        if (ch < 3) {                   // prefetch next chunk; compute hides it
            int off = (ch + 1) * 32;
            av  = *(const float4*)(pa + off);
            bv0 = *(const float4*)(pb0 + off);
            bv1 = *(const float4*)(pb1 + off);
        }
        #pragma unroll
        for (int oct = 0; oct < 4; ++oct) {
            int h0 = oct * 8;
            const float* wp = wsv + ch * 32 + h0;   // uniform -> s_load
            float w0 = wp[0], w1 = wp[1], w2 = wp[2], w3 = wp[3];
            float w4 = wp[4], w5 = wp[5], w6 = wp[6], w7 = wp[7];
            float4 ap0 = *(const float4*)&Al[ty][h0];
            float4 ap1 = *(const float4*)&Al[ty][h0 + 4];
            float4 aq0 = *(const float4*)&Al[ty + 16][h0];
            float4 aq1 = *(const float4*)&Al[ty + 16][h0 + 4];
            #pragma unroll
            for (int j = 0; j < 4; ++j) {
                float4 p = *(const float4*)&Bl[tx + 16 * j][h0];
                float4 q = *(const float4*)&Bl[tx + 16 * j][h0 + 4];
                PAIR(ap0.x, ap0.y, p.x, p.y, w0, w1, acc[0][j]);
                PAIR(ap0.z, ap0.w, p.z, p.w, w2, w3, acc[0][j]);
                PAIR(ap1.x, ap1.y, q.x, q.y, w4, w5, acc[0][j]);
                PAIR(ap1.z, ap1.w, q.z, q.w, w6, w7, acc[0][j]);
                PAIR(aq0.x, aq0.y, p.x, p.y, w0, w1, acc[1][j]);
                PAIR(aq0.z, aq0.w, p.z, p.w, w2, w3, acc[1][j]);
                PAIR(aq1.x, aq1.y, q.x, q.y, w4, w5, acc[1][j]);
                PAIR(aq1.z, aq1.w, q.z, q.w, w6, w7, acc[1][j]);
            }
        }
    }

    // ---- epilogue: stage [64m][32n] tile in Bl, nontemporal v4f writes ----
    __syncthreads();
    #pragma unroll
    for (int j = 0; j < 4; ++j)
        #pragma unroll
        for (int i = 0; i < 2; ++i)
            Bl[tx + 16 * j][ty + 16 * i] = -2.0f * acc[i][j];
    __syncthreads();
    {
        int r = tid >> 3;            // 0..31
        int c = (tid & 7) * 4;       // 0..28
        v4f o0 = *(const v4f*)&Bl[r][c];
        __builtin_nontemporal_store(o0, (v4f*)(St + (size_t)(m0 + r) * N + n0 + c));
        v4f o1 = *(const v4f*)&Bl[r + 32][c];
        __builtin_nontemporal_store(o1, (v4f*)(St + (size_t)(m0 + r + 32) * N + n0 + c));
    }
}

// ---- fused softmax-stats + context + final MLP ---------------------------
#define TMD 4
__device__ __forceinline__ void reduce4(float v[TMD], bool domax, float (*scr)[TMD]) {
    #pragma unroll
    for (int off = 32; off > 0; off >>= 1) {
        #pragma unroll
        for (int j = 0; j < TMD; ++j) {
            float o = __shfl_xor(v[j], off, 64);
            v[j] = domax ? fmaxf(v[j], o) : (v[j] + o);
        }
    }
    int wv = threadIdx.x >> 6;     // 0..15
    if ((threadIdx.x & 63) == 0) {
        #pragma unroll
        for (int j = 0; j < TMD; ++j) scr[wv][j] = v[j];
    }
    __syncthreads();
    #pragma unroll
    for (int j = 0; j < TMD; ++j) {
        float r = scr[0][j];
        #pragma unroll
        for (int i = 1; i < 16; ++i) r = domax ? fmaxf(r, scr[i][j]) : (r + scr[i][j]);
        v[j] = r;
    }
    __syncthreads();
}

__global__ __launch_bounds__(1024) void k_attend(const float* __restrict__ St_s,
                                                 const float* __restrict__ St_e,
                                                 const float* __restrict__ stmts,
                                                 const float* __restrict__ eres,
                                                 const float* __restrict__ attender,
                                                 const float* __restrict__ WT_lin,
                                                 const float* __restrict__ b_lin,
                                                 const float* __restrict__ W_coh,
                                                 const float* __restrict__ b_coh,
                                                 float* __restrict__ out) {
    __shared__ float wls[1024][TMD];       // 16 KB, 16B rows: b128 in/out
    __shared__ float part[8][TMD][H];
    __shared__ float feats[TMD][3 * H];
    __shared__ float scr[16][TMD];
    __shared__ float redv[512];
    __shared__ float red8[8];
    int m0  = blockIdx.x * TMD;
    int tid = threadIdx.x;
    int h   = tid & (H - 1);
    int g   = tid >> 7;    // 0..7

    if (tid < TMD * H) feats[tid >> 7][tid & (H - 1)] = attender[(m0 + (tid >> 7)) * H + (tid & (H - 1))];

    float vs[TMD], ve[TMD];
    #pragma unroll
    for (int j = 0; j < TMD; ++j)
        vs[j] = __builtin_nontemporal_load(St_s + (size_t)(m0 + j) * NS + tid);
    #pragma unroll
    for (int j = 0; j < TMD; ++j)
        ve[j] = (tid < NE) ? __builtin_nontemporal_load(St_e + (size_t)(m0 + j) * NE + tid) : -1e30f;

    float mxs[TMD], sm_s[TMD], rz_s[TMD], w_s[TMD];
    #pragma unroll
    for (int j = 0; j < TMD; ++j) mxs[j] = vs[j];
    reduce4(mxs, true, scr);
    #pragma unroll
    for (int j = 0; j < TMD; ++j) { w_s[j] = __expf(vs[j] - mxs[j]); sm_s[j] = w_s[j]; }
    reduce4(sm_s, false, scr);
    #pragma unroll
    for (int j = 0; j < TMD; ++j) rz_s[j] = __builtin_amdgcn_rcpf(sm_s[j]);

    float mxe[TMD], sm_e[TMD], rz_e[TMD], w_e[TMD];
    #pragma unroll
    for (int j = 0; j < TMD; ++j) mxe[j] = ve[j];
    reduce4(mxe, true, scr);
    #pragma unroll
    for (int j = 0; j < TMD; ++j) { w_e[j] = __expf(ve[j] - mxe[j]); sm_e[j] = w_e[j]; }
    reduce4(sm_e, false, scr);
    #pragma unroll
    for (int j = 0; j < TMD; ++j) rz_e[j] = __builtin_amdgcn_rcpf(sm_e[j]);

    // ---- ctx_s ----
    *(float4*)&wls[tid][0] = make_float4(w_s[0], w_s[1], w_s[2], w_s[3]);
    __syncthreads();
    {
        float acc[TMD] = {0.f, 0.f, 0.f, 0.f};
        const float* Xb = stmts + (size_t)(g * 128) * H + h;
        #pragma unroll 8
        for (int nn = 0; nn < 128; ++nn) {
            float x = Xb[(size_t)nn * H];
            float4 w4 = *(const float4*)&wls[g * 128 + nn][0];
            acc[0] += w4.x * x; acc[1] += w4.y * x;
            acc[2] += w4.z * x; acc[3] += w4.w * x;
        }
        #pragma unroll
        for (int j = 0; j < TMD; ++j) part[g][j][h] = acc[j];
    }
    __syncthreads();
    if (tid < 512) {
        int j = tid >> 7, hh = tid & 127;
        float s = 0.f;
        #pragma unroll
        for (int gg = 0; gg < 8; ++gg) s += part[gg][j][hh];
        feats[j][H + hh] = s * rz_s[j];
    }
    __syncthreads();

    // ---- ctx_e ----
    *(float4*)&wls[tid][0] = make_float4(w_e[0], w_e[1], w_e[2], w_e[3]);
    __syncthreads();
    {
        float acc[TMD] = {0.f, 0.f, 0.f, 0.f};
        const float* Xb = eres + (size_t)(g * 64) * H + h;
        #pragma unroll 8
        for (int nn = 0; nn < 64; ++nn) {
            float x = Xb[(size_t)nn * H];
            float4 w4 = *(const float4*)&wls[g * 64 + nn][0];
            acc[0] += w4.x * x; acc[1] += w4.y * x;
            acc[2] += w4.z * x; acc[3] += w4.w * x;
        }
        #pragma unroll
        for (int j = 0; j < TMD; ++j) part[g][j][h] = acc[j];
    }
    __syncthreads();
    if (tid < 512) {
        int j = tid >> 7, hh = tid & 127;
        float s = 0.f;
        #pragma unroll
        for (int gg = 0; gg < 8; ++gg) s += part[gg][j][hh];
        feats[j][2 * H + hh] = s * rz_e[j];
    }
    __syncthreads();

    // ---- final MLP + coherence ----
    {
        int a    = tid & 127;
        int jm   = (tid >> 7) & 3;
        int half = tid >> 9;
        float acc = half ? 0.f : b_lin[a];
        int k0 = half * 192;
        #pragma unroll 8
        for (int k = k0; k < k0 + 192; ++k)
            acc += feats[jm][k] * WT_lin[k * H + a];
        if (half) redv[tid & 511] = acc;
        __syncthreads();
        if (!half) {
            acc += redv[tid];
            float v = fast_tanh(acc) * W_coh[a];
            #pragma unroll
            for (int off = 32; off > 0; off >>= 1) v += __shfl_down(v, off, 64);
            if ((tid & 63) == 0) red8[tid >> 6] = v;
        }
        __syncthreads();
        if (tid < TMD) out[m0 + tid] = red8[2 * tid] + red8[2 * tid + 1] + b_coh[0];
    }
}

extern "C" void kernel_launch(void* const* d_in, const int* in_sizes, int n_in,
                              void* d_out, int out_size, void* d_ws, size_t ws_size,
                              hipStream_t stream) {
    const float* stmts    = (const float*)d_in[0];
    const float* eres     = (const float*)d_in[1];
    const float* attender = (const float*)d_in[2];
    const float* Wc_s     = (const float*)d_in[3];
    const float* bc_s     = (const float*)d_in[4];
    const float* ws_s     = (const float*)d_in[5];
    const float* Wc_e     = (const float*)d_in[7];
    const float* bc_e     = (const float*)d_in[8];
    const float* ws_e     = (const float*)d_in[9];
    const float* W_lin    = (const float*)d_in[11];
    const float* b_lin    = (const float*)d_in[12];
    const float* W_coh    = (const float*)d_in[13];
    const float* b_coh    = (const float*)d_in[14];
    float* out = (float*)d_out;

    float* ws    = (float*)d_ws;
    float* WT_s1 = ws;
    float* WT_s2 = WT_s1 + H * H;
    float* WT_e1 = WT_s2 + H * H;
    float* WT_e2 = WT_e1 + H * H;
    float* WT_li = WT_e2 + H * H;             // 384*128
    float* EA_s  = WT_li + 3 * H * H;
    float* EB_s  = EA_s + NS * H;
    float* EA_e  = EB_s + M * H;
    float* EB_e  = EA_e + NE * H;
    float* St_s  = EB_e + M * H;
    float* St_e  = St_s + (size_t)M * NS;

    k_tr<<<448, 256, 0, stream>>>(Wc_s, Wc_e, W_lin, WT_s1, WT_s2, WT_e1, WT_e2, WT_li);
    k_proj<<<896, 256, 0, stream>>>(stmts, eres, attender, WT_s1, WT_s2, WT_e1, WT_e2,
                                    bc_s, bc_e, EA_s, EB_s, EA_e, EB_e);
    k_score<<<dim3(16, 48), 256, 0, stream>>>(EA_s, EB_s, ws_s, EA_e, EB_e, ws_e, St_s, St_e);
    k_attend<<<M / TMD, 1024, 0, stream>>>(St_s, St_e, stmts, eres, attender, WT_li,
                                           b_lin, W_coh, b_coh, out);
}